// Round 13
// baseline (7919.472 us; speedup 1.0000x reference)
//
#include <hip/hip_runtime.h>
#include <math.h>

#define NL 24
#define NB 64
#define TPB 512
#define QROWS 765
// ---- ws layout (float units) ----
#define RING_F  3133440                    // [64][765][64]
#define MB_OFF  RING_F                     // M matrices: [24][64][128]
#define CB2_OFF (MB_OFF + 24*64*128)       // folded conv bias: [24][128]
#define CV_OFF  (CB2_OFF + 24*128)         // conv pack: 24*512*12 f4
#define RS_OFF  (CV_OFF + 24*512*48)       // res+skip pack: 24*512*10 f4
#define PH_OFF  (RS_OFF + 24*512*40)       // head pack: 16*32*64 f4

typedef float vf4 __attribute__((ext_vector_type(4)));

struct WBc  { float4 v[12]; };   // 3-term conv frag (48 VGPR), double-buffered
struct WBrs { float4 v[10]; };   // res+skip frag (40 VGPR), single, per-phase

__device__ __forceinline__ float hadd4(float4 v) { return (v.x + v.y) + (v.z + v.w); }
__device__ __forceinline__ void fma4(float4& a, float4 x, float4 w) {
    a.x = fmaf(x.x, w.x, a.x); a.y = fmaf(x.y, w.y, a.y);
    a.z = fmaf(x.z, w.z, a.z); a.w = fmaf(x.w, w.w, a.w);
}
// barrier WITHOUT vmcnt drain (prefetches stay in flight)
__device__ __forceinline__ void bar() {
    asm volatile("s_waitcnt lgkmcnt(0)" ::: "memory");
    __builtin_amdgcn_s_barrier();
    asm volatile("" ::: "memory");
}
__device__ __forceinline__ void pf_cv(WBc& b, const float4* __restrict__ cvp, int layer, int tid) {
    const float4* p = cvp + (size_t)layer * (12 * 512) + tid;
#pragma unroll
    for (int j = 0; j < 12; ++j) b.v[j] = p[j * 512];
}
__device__ __forceinline__ void pf_rs(WBrs& b, const float4* __restrict__ rsp, int layer, int tid) {
    const float4* p = rsp + (size_t)layer * (10 * 512) + tid;
#pragma unroll
    for (int j = 0; j < 10; ++j) b.v[j] = p[j * 512];
}

// ---------------- repack1: M_i = R_{i-1} @ K1_i ; cb2_i = cb_i + rb_{i-1} @ K1_i ----------------
__global__ void repack1(const float* __restrict__ conv_k, const float* __restrict__ res_w,
                        const float* __restrict__ conv_b, const float* __restrict__ res_b,
                        float* __restrict__ ws) {
    const int i = blockIdx.x, col = threadIdx.x;   // 24 x 128
    float* M   = ws + MB_OFF;
    float* cb2 = ws + CB2_OFF;
    if (i == 0) {
        for (int m = 0; m < 64; ++m) M[(size_t)m * 128 + col] = 0.f;
        cb2[col] = conv_b[col];
        return;
    }
    float k1[64];
#pragma unroll
    for (int k = 0; k < 64; ++k)
        k1[k] = conv_k[((size_t)(i * 2 + 1) * 64 + k) * 128 + col];
    for (int m = 0; m < 64; ++m) {
        float a = 0.f;
#pragma unroll
        for (int k = 0; k < 64; ++k)
            a = fmaf(res_w[((size_t)(i - 1) * 64 + m) * 64 + k], k1[k], a);
        M[((size_t)i * 64 + m) * 128 + col] = a;
    }
    float cb = conv_b[i * 128 + col];
#pragma unroll
    for (int k = 0; k < 64; ++k)
        cb = fmaf(res_b[(i - 1) * 64 + k], k1[k], cb);
    cb2[i * 128 + col] = cb;
}

// ---------------- repack2: build CV / RS / PH lane-major packs ----------------
__global__ void repack2(const float* __restrict__ conv_k, const float* __restrict__ res_w,
                        const float* __restrict__ skip_w, const float* __restrict__ out0_w,
                        const float* __restrict__ out1_w, float* __restrict__ ws) {
    const int bb = blockIdx.x, tid = threadIdx.x;
    float4* CV = (float4*)(ws + CV_OFF);
    float4* RS = (float4*)(ws + RS_OFF);
    float4* PH = (float4*)(ws + PH_OFF);
    const float* M = ws + MB_OFF;
    if (bb < NL) {
        const int i = bb, w = tid >> 6, l = tid & 63;
        const int c  = w * 8 + (l & 7);
        const int k0 = (l >> 3) * 8;
        float4* dst = CV + (size_t)i * (12 * 512) + tid;
#pragma unroll
        for (int half = 0; half < 2; ++half) {
            const int cc = c + half * 64;
#pragma unroll
            for (int jj = 0; jj < 2; ++jj) {
                const int kk = k0 + jj * 4;
                float4 a, b, m;
                a.x = conv_k[((size_t)(i * 2 + 0) * 64 + kk + 0) * 128 + cc];
                a.y = conv_k[((size_t)(i * 2 + 0) * 64 + kk + 1) * 128 + cc];
                a.z = conv_k[((size_t)(i * 2 + 0) * 64 + kk + 2) * 128 + cc];
                a.w = conv_k[((size_t)(i * 2 + 0) * 64 + kk + 3) * 128 + cc];
                b.x = conv_k[((size_t)(i * 2 + 1) * 64 + kk + 0) * 128 + cc];
                b.y = conv_k[((size_t)(i * 2 + 1) * 64 + kk + 1) * 128 + cc];
                b.z = conv_k[((size_t)(i * 2 + 1) * 64 + kk + 2) * 128 + cc];
                b.w = conv_k[((size_t)(i * 2 + 1) * 64 + kk + 3) * 128 + cc];
                m.x = M[((size_t)i * 64 + kk + 0) * 128 + cc];
                m.y = M[((size_t)i * 64 + kk + 1) * 128 + cc];
                m.z = M[((size_t)i * 64 + kk + 2) * 128 + cc];
                m.w = M[((size_t)i * 64 + kk + 3) * 128 + cc];
                dst[(half * 6 + 0 + jj) * 512] = a;
                dst[(half * 6 + 2 + jj) * 512] = b;
                dst[(half * 6 + 4 + jj) * 512] = m;
            }
        }
        float4* rdst = RS + (size_t)i * (10 * 512) + tid;
#pragma unroll
        for (int jj = 0; jj < 2; ++jj) {            // res col c, K-chunk k0
            float4 v; const int kk = k0 + jj * 4;
            v.x = res_w[((size_t)i * 64 + kk + 0) * 64 + c];
            v.y = res_w[((size_t)i * 64 + kk + 1) * 64 + c];
            v.z = res_w[((size_t)i * 64 + kk + 2) * 64 + c];
            v.w = res_w[((size_t)i * 64 + kk + 3) * 64 + c];
            rdst[jj * 512] = v;
        }
        const int s0 = w * 32 + (l & 15) * 2;
        const int ks = (l >> 4) * 16;
#pragma unroll
        for (int jj = 0; jj < 4; ++jj) {            // skip col s0
            float4 v; const int kk = ks + jj * 4;
            v.x = skip_w[((size_t)i * 64 + kk + 0) * 256 + s0];
            v.y = skip_w[((size_t)i * 64 + kk + 1) * 256 + s0];
            v.z = skip_w[((size_t)i * 64 + kk + 2) * 256 + s0];
            v.w = skip_w[((size_t)i * 64 + kk + 3) * 256 + s0];
            rdst[(2 + jj) * 512] = v;
        }
#pragma unroll
        for (int jj = 0; jj < 4; ++jj) {            // skip col s0+1
            float4 v; const int kk = ks + jj * 4; const int s1 = s0 + 1;
            v.x = skip_w[((size_t)i * 64 + kk + 0) * 256 + s1];
            v.y = skip_w[((size_t)i * 64 + kk + 1) * 256 + s1];
            v.z = skip_w[((size_t)i * 64 + kk + 2) * 256 + s1];
            v.w = skip_w[((size_t)i * 64 + kk + 3) * 256 + s1];
            rdst[(6 + jj) * 512] = v;
        }
    } else {
        if (tid >= 64) return;
        const int hb = bb - NL;                     // 0..15: [which][wave]
        const int which = hb >> 3, w = hb & 7, l = tid;
        const float* W = which ? out1_w : out0_w;
        float4* dst = PH + (size_t)hb * (32 * 64) + l;
        const int c  = w * 32 + (l & 31);
        const int kb = (l >> 5) * 128;
        for (int j = 0; j < 32; ++j) {
            float4 v; const int k0 = kb + j * 4;
            v.x = W[(size_t)(k0 + 0) * 256 + c];
            v.y = W[(size_t)(k0 + 1) * 256 + c];
            v.z = W[(size_t)(k0 + 2) * 256 + c];
            v.w = W[(size_t)(k0 + 3) * 256 + c];
            dst[j * 64] = v;
        }
    }
}

// ---------------- main generator: one phase per layer (24+4 barriers/step) ----------------
__global__ __launch_bounds__(TPB, 1)
void wavenet_gen(const int* __restrict__ seed,
                 const float* __restrict__ embed,
                 const float* __restrict__ res_b,
                 const float* __restrict__ skip_b,
                 const float* __restrict__ out0_b,
                 const float* __restrict__ out1_b,
                 const int* __restrict__ Tptr,
                 float* __restrict__ out,
                 float* __restrict__ ring,
                 const float4* __restrict__ cvp,
                 const float4* __restrict__ rsp,
                 const float4* __restrict__ php,
                 const float* __restrict__ cb2p)
{
    const int b   = blockIdx.x;
    const int tid = threadIdx.x;
    const int w   = tid >> 6;
    const int l   = tid & 63;
    const int T   = *Tptr;

    __shared__ __align__(16) float xl[2][64];        // xlast ping-pong
    __shared__ __align__(16) float yb[2][64];        // layer-input ping-pong (y_j in yb[j&1])
    __shared__ __align__(16) float gb[2][64];        // gate ping-pong (g_j in gb[j&1])
    __shared__ __align__(16) float skl[256];
    __shared__ __align__(16) float h0l[256];
    __shared__ __align__(16) float ebt[256 * 64];
    __shared__ __align__(16) float cb2S[NL * 128];
    __shared__ __align__(16) float rbS[NL * 64];
    __shared__ __align__(16) float o0bS[256], o1bS[256], sbtS[256];
    __shared__ float wmaxv[8];
    __shared__ int   wmaxi[8];

    float* q = ring + (size_t)b * (QROWS * 64);

    // ---- init ----
    {
        vf4* q4 = (vf4*)q;
        const vf4 z = (vf4){0.f, 0.f, 0.f, 0.f};
        for (int idx = tid; idx < QROWS * 64 / 4; idx += TPB)
            __builtin_nontemporal_store(z, &q4[idx]);
        const float4* s4; float4* d4;
        s4 = (const float4*)embed;  d4 = (float4*)ebt;
        for (int idx = tid; idx < 256 * 64 / 4; idx += TPB) d4[idx] = s4[idx];
        s4 = (const float4*)cb2p;   d4 = (float4*)cb2S;
        for (int idx = tid; idx < NL * 128 / 4; idx += TPB) d4[idx] = s4[idx];
        s4 = (const float4*)res_b;  d4 = (float4*)rbS;
        for (int idx = tid; idx < NL * 64 / 4; idx += TPB) d4[idx] = s4[idx];
        s4 = (const float4*)out0_b; d4 = (float4*)o0bS;
        for (int idx = tid; idx < 64; idx += TPB) d4[idx] = s4[idx];
        s4 = (const float4*)out1_b; d4 = (float4*)o1bS;
        for (int idx = tid; idx < 64; idx += TPB) d4[idx] = s4[idx];
        if (tid < 256) {
            float acc = 0.f;
            for (int i = 0; i < NL; ++i) acc += skip_b[i * 256 + tid];
            sbtS[tid] = acc;
        }
    }
    __syncthreads();
    if (tid < 64) {
        const int smp = seed[b];
        yb[0][tid] = ebt[smp * 64 + tid];   // y_0(t=0)
        yb[1][tid] = 0.f;
        xl[0][tid] = 0.f;                   // xlast_0(t=0)
        xl[1][tid] = 0.f;
        gb[0][tid] = 0.f;                   // avoid NaN*0 in layer-0 M-term
        gb[1][tid] = 0.f;
    }
    __syncthreads();

    WBc  CVa, CVb;
    WBrs RS;
    pf_cv(CVa, cvp, 0, tid);

    float* out_pred = out + (size_t)b * T;
    float* out_log  = out + (size_t)NB * T + (size_t)b * T * 256;

    const int c   = w * 8 + (l & 7);
    const int k0  = (l >> 3) * 8;          // conv/res K-chunk
    const int ks  = (l >> 4) * 16;         // skip K-chunk
    const int s0  = w * 32 + (l & 15) * 2;
    const int c2  = w * 32 + (l & 31);
    const int kb2 = (l >> 5) * 128;

    float skv0 = 0.f, skv1 = 0.f;

    for (int t = 0; t < T; ++t) {

        auto phase = [&](WBc& cur, WBc& nxt, const int i) {
            const int j = (i + 1 < NL) ? (i + 1) : 0;
            // ---- issue: ring read (xlast_j) FIRST, then RS_{i-1}, then CV_j ----
            float xln = 0.f;
            if (w == 7) {
                const int dj = 1 << (j & 7);
                const int s  = (i == NL - 1) ? (t + 1) : t;
                const int row = 255 * (j >> 3) + (dj - 1) + (s & (dj - 1));
                xln = __builtin_nontemporal_load(&q[(size_t)row * 64 + l]);
            }
            if (i) pf_rs(RS, rsp, i - 1, tid);
            pf_cv(nxt, cvp, j, tid);
            if (w == 6 && i) {              // push row(i-1, t) = y_{i-1}(t)
                const int dp = 1 << ((i - 1) & 7);
                const int row = 255 * ((i - 1) >> 3) + (dp - 1) + (t & (dp - 1));
                __builtin_nontemporal_store(yb[(i - 1) & 1][l], &q[(size_t)row * 64 + l]);
            }
            const int ybi = i ? ((i - 1) & 1) : 0;   // buffer holding y_{i-1} (or y_0 for i=0)
            const int gbi = (i - 1) & 1;             // buffer holding g_{i-1} (garbage*0 for i=0)
            // ---- 3-term conv ----
            const float4 xl0 = *(const float4*)&xl[i & 1][k0];
            const float4 xl1 = *(const float4*)&xl[i & 1][k0 + 4];
            const float4 yp0 = *(const float4*)&yb[ybi][k0];
            const float4 yp1 = *(const float4*)&yb[ybi][k0 + 4];
            const float4 gp0 = *(const float4*)&gb[gbi][k0];
            const float4 gp1 = *(const float4*)&gb[gbi][k0 + 4];
            float4 aA = make_float4(0.f, 0.f, 0.f, 0.f);
            float4 aB = make_float4(0.f, 0.f, 0.f, 0.f);
            fma4(aA, xl0, cur.v[0]); fma4(aA, xl1, cur.v[1]);
            fma4(aA, yp0, cur.v[2]); fma4(aA, yp1, cur.v[3]);
            fma4(aA, gp0, cur.v[4]); fma4(aA, gp1, cur.v[5]);
            fma4(aB, xl0, cur.v[6]); fma4(aB, xl1, cur.v[7]);
            fma4(aB, yp0, cur.v[8]); fma4(aB, yp1, cur.v[9]);
            fma4(aB, gp0, cur.v[10]); fma4(aB, gp1, cur.v[11]);
            float hA = hadd4(aA), hB = hadd4(aB);
            hA += __shfl_xor(hA, 8);  hB += __shfl_xor(hB, 8);
            hA += __shfl_xor(hA, 16); hB += __shfl_xor(hB, 16);
            hA += __shfl_xor(hA, 32); hB += __shfl_xor(hB, 32);
            hA += cb2S[i * 128 + c];
            hB += cb2S[i * 128 + 64 + c];
            const float g = tanhf(hA) * (1.f / (1.f + expf(-hB)));
            // ---- deferred res + skip of layer i-1 ----
            float ynew = 0.f;
            if (i) {
                float4 ra = make_float4(0.f, 0.f, 0.f, 0.f);
                fma4(ra, gp0, RS.v[0]); fma4(ra, gp1, RS.v[1]);
                float racc = hadd4(ra);
                racc += __shfl_xor(racc, 8);
                racc += __shfl_xor(racc, 16);
                racc += __shfl_xor(racc, 32);
                ynew = yb[ybi][c] + racc + rbS[(i - 1) * 64 + c];
                const float4 gs0 = *(const float4*)&gb[gbi][ks];
                const float4 gs1 = *(const float4*)&gb[gbi][ks + 4];
                const float4 gs2 = *(const float4*)&gb[gbi][ks + 8];
                const float4 gs3 = *(const float4*)&gb[gbi][ks + 12];
                float4 sa0 = make_float4(0.f, 0.f, 0.f, 0.f);
                float4 sa1 = make_float4(0.f, 0.f, 0.f, 0.f);
                fma4(sa0, gs0, RS.v[2]); fma4(sa0, gs1, RS.v[3]);
                fma4(sa0, gs2, RS.v[4]); fma4(sa0, gs3, RS.v[5]);
                fma4(sa1, gs0, RS.v[6]); fma4(sa1, gs1, RS.v[7]);
                fma4(sa1, gs2, RS.v[8]); fma4(sa1, gs3, RS.v[9]);
                float ss0 = hadd4(sa0), ss1 = hadd4(sa1);
                ss0 += __shfl_xor(ss0, 16); ss1 += __shfl_xor(ss1, 16);
                ss0 += __shfl_xor(ss0, 32); ss1 += __shfl_xor(ss1, 32);
                skv0 += ss0;
                skv1 += ss1;
            }
            // ---- publish ----
            if (l < 8) gb[i & 1][w * 8 + l] = g;
            if (i && l < 8) yb[i & 1][w * 8 + l] = ynew;
            if (w == 7) xl[j & 1][l] = xln;
            bar();
        };

#pragma unroll 1
        for (int ii = 0; ii < NL; ii += 2) {
            phase(CVa, CVb, ii);
            phase(CVb, CVa, ii + 1);
        }

        // ---------------- head phase A: skip_23, finalize sk, push row(23) ----------------
        {
            pf_rs(RS, rsp, NL - 1, tid);
            const float4 gs0 = *(const float4*)&gb[1][ks];
            const float4 gs1 = *(const float4*)&gb[1][ks + 4];
            const float4 gs2 = *(const float4*)&gb[1][ks + 8];
            const float4 gs3 = *(const float4*)&gb[1][ks + 12];
            float4 sa0 = make_float4(0.f, 0.f, 0.f, 0.f);
            float4 sa1 = make_float4(0.f, 0.f, 0.f, 0.f);
            fma4(sa0, gs0, RS.v[2]); fma4(sa0, gs1, RS.v[3]);
            fma4(sa0, gs2, RS.v[4]); fma4(sa0, gs3, RS.v[5]);
            fma4(sa1, gs0, RS.v[6]); fma4(sa1, gs1, RS.v[7]);
            fma4(sa1, gs2, RS.v[8]); fma4(sa1, gs3, RS.v[9]);
            float ss0 = hadd4(sa0), ss1 = hadd4(sa1);
            ss0 += __shfl_xor(ss0, 16); ss1 += __shfl_xor(ss1, 16);
            ss0 += __shfl_xor(ss0, 32); ss1 += __shfl_xor(ss1, 32);
            skv0 += ss0;
            skv1 += ss1;
            if (l < 16) {
                skl[s0] = skv0 + sbtS[s0];
                skl[s0 + 1] = skv1 + sbtS[s0 + 1];
            }
            skv0 = 0.f; skv1 = 0.f;
            if (w == 6) {                   // push row(23, t) = y_23(t)
                const int row = 510 + 127 + (t & 127);
                __builtin_nontemporal_store(yb[1][l], &q[(size_t)row * 64 + l]);
            }
            bar();
        }
        // ---------------- head B: GEMV1 ----------------
        {
            const float4* hp = php + ((size_t)w * 32) * 64 + l;
            float4 ha = make_float4(0.f, 0.f, 0.f, 0.f);
#pragma unroll 8
            for (int cc = 0; cc < 32; ++cc) {
                float4 wv = hp[cc * 64];
                float4 sv = *(const float4*)&skl[kb2 + cc * 4];
                fma4(ha, sv, wv);
            }
            float hs = hadd4(ha);
            hs += __shfl_xor(hs, 32);
            const float h0 = fmaxf(hs + o0bS[c2], 0.f);
            if (l < 32) h0l[c2] = h0;
        }
        bar();
        // ---------------- head C: GEMV2 + wave argmax ----------------
        {
            const float4* hp = php + ((size_t)(8 + w) * 32) * 64 + l;
            float4 la = make_float4(0.f, 0.f, 0.f, 0.f);
#pragma unroll 8
            for (int cc = 0; cc < 32; ++cc) {
                float4 wv = hp[cc * 64];
                float4 hv = *(const float4*)&h0l[kb2 + cc * 4];
                fma4(la, hv, wv);
            }
            float ls = hadd4(la);
            ls += __shfl_xor(ls, 32);
            const float logit = ls + o1bS[c2];
            if (l < 32)
                __builtin_nontemporal_store(logit, &out_log[(size_t)t * 256 + c2]);
            float bv = logit; int bi = c2;
#pragma unroll
            for (int off = 1; off <= 16; off <<= 1) {
                const float ov = __shfl_xor(bv, off);
                const int   oi = __shfl_xor(bi, off);
                if (ov > bv || (ov == bv && oi < bi)) { bv = ov; bi = oi; }
            }
            if (l == 0) { wmaxv[w] = bv; wmaxi[w] = bi; }
        }
        bar();
        // ---------------- head D: final argmax, y_0(t+1), mu-law ----------------
        {
            float fv = wmaxv[0]; int fi = wmaxi[0];
#pragma unroll
            for (int ww = 1; ww < 8; ++ww) {
                const float vv = wmaxv[ww]; const int vi = wmaxi[ww];
                if (vv > fv || (vv == fv && vi < fi)) { fv = vv; fi = vi; }
            }
            if (tid < 64) yb[0][tid] = ebt[fi * 64 + tid];   // y_0 of next step
            if (tid == 0) {
                const float mw = (float)fi * (2.0f / 255.0f) - 1.0f;
                const float a  = fabsf(mw);
                const float p  = (exp2f(8.0f * a) - 1.0f) * (1.0f / 255.0f);
                __builtin_nontemporal_store((mw < 0.f) ? -p : p, &out_pred[t]);
            }
        }
        bar();
    }
}

extern "C" void kernel_launch(void* const* d_in, const int* in_sizes, int n_in,
                              void* d_out, int out_size, void* d_ws, size_t ws_size,
                              hipStream_t stream) {
    const int*   seed   = (const int*)  d_in[0];
    const float* embed  = (const float*)d_in[1];
    const float* conv_k = (const float*)d_in[2];
    const float* conv_b = (const float*)d_in[3];
    const float* res_w  = (const float*)d_in[4];
    const float* res_b  = (const float*)d_in[5];
    const float* skip_w = (const float*)d_in[6];
    const float* skip_b = (const float*)d_in[7];
    const float* out0_w = (const float*)d_in[8];
    const float* out0_b = (const float*)d_in[9];
    const float* out1_w = (const float*)d_in[10];
    const float* out1_b = (const float*)d_in[11];
    const int*   Tptr   = (const int*)  d_in[12];

    float* ws = (float*)d_ws;
    float* ring = ws;
    const float4* cvp  = (const float4*)(ws + CV_OFF);
    const float4* rsp  = (const float4*)(ws + RS_OFF);
    const float4* php  = (const float4*)(ws + PH_OFF);
    const float*  cb2p = ws + CB2_OFF;

    repack1<<<dim3(NL), dim3(128), 0, stream>>>(conv_k, res_w, conv_b, res_b, ws);
    repack2<<<dim3(NL + 16), dim3(512), 0, stream>>>(conv_k, res_w, skip_w, out0_w, out1_w, ws);

    wavenet_gen<<<dim3(NB), dim3(TPB), 0, stream>>>(
        seed, embed, res_b, skip_b, out0_b, out1_b, Tptr,
        (float*)d_out, ring, cvp, rsp, php, cb2p);
}

// Round 14
// 7905.969 us; speedup vs baseline: 1.0017x; 1.0017x over previous
//
#include <hip/hip_runtime.h>
#include <math.h>

#define NL 24
#define NB 64
#define TPB 512
#define QROWS 765
// ---- ws layout (float units) ----
#define RING_F  3133440                    // [64][765][64]
#define MB_OFF  RING_F                     // M matrices: [24][64][128]
#define CB2_OFF (MB_OFF + 24*64*128)       // folded conv bias: [24][128]
#define CV_OFF  (CB2_OFF + 24*128)         // conv pack: 24*512*12 f4
#define RS_OFF  (CV_OFF + 24*512*48)       // res+skip pack: 24*512*10 f4
#define PH_OFF  (RS_OFF + 24*512*40)       // head pack: 16*32*64 f4

typedef float vf4 __attribute__((ext_vector_type(4)));

struct WBc  { float4 v[12]; };   // 3-term conv frag (48 VGPR), double-buffered
struct WBrs { float4 v[10]; };   // res+skip frag (40 VGPR), single, per-phase

__device__ __forceinline__ float hadd4(float4 v) { return (v.x + v.y) + (v.z + v.w); }
__device__ __forceinline__ void fma4(float4& a, float4 x, float4 w) {
    a.x = fmaf(x.x, w.x, a.x); a.y = fmaf(x.y, w.y, a.y);
    a.z = fmaf(x.z, w.z, a.z); a.w = fmaf(x.w, w.w, a.w);
}
// barrier WITHOUT vmcnt drain (prefetches stay in flight)
__device__ __forceinline__ void bar() {
    asm volatile("s_waitcnt lgkmcnt(0)" ::: "memory");
    __builtin_amdgcn_s_barrier();
    asm volatile("" ::: "memory");
}
__device__ __forceinline__ void pf_cv(WBc& b, const float4* __restrict__ cvp, int layer, int tid) {
    const float4* p = cvp + (size_t)layer * (12 * 512) + tid;
#pragma unroll
    for (int j = 0; j < 12; ++j) b.v[j] = p[j * 512];
}
__device__ __forceinline__ void pf_rs(WBrs& b, const float4* __restrict__ rsp, int layer, int tid) {
    const float4* p = rsp + (size_t)layer * (10 * 512) + tid;
#pragma unroll
    for (int j = 0; j < 10; ++j) b.v[j] = p[j * 512];
}

// ---------------- repack1: M_i = R_{i-1} @ K1_i ; cb2_i = cb_i + rb_{i-1} @ K1_i ----------------
__global__ void repack1(const float* __restrict__ conv_k, const float* __restrict__ res_w,
                        const float* __restrict__ conv_b, const float* __restrict__ res_b,
                        float* __restrict__ ws) {
    const int i = blockIdx.x, col = threadIdx.x;   // 24 x 128
    float* M   = ws + MB_OFF;
    float* cb2 = ws + CB2_OFF;
    if (i == 0) {
        for (int m = 0; m < 64; ++m) M[(size_t)m * 128 + col] = 0.f;
        cb2[col] = conv_b[col];
        return;
    }
    float k1[64];
#pragma unroll
    for (int k = 0; k < 64; ++k)
        k1[k] = conv_k[((size_t)(i * 2 + 1) * 64 + k) * 128 + col];
    for (int m = 0; m < 64; ++m) {
        float a = 0.f;
#pragma unroll
        for (int k = 0; k < 64; ++k)
            a = fmaf(res_w[((size_t)(i - 1) * 64 + m) * 64 + k], k1[k], a);
        M[((size_t)i * 64 + m) * 128 + col] = a;
    }
    float cb = conv_b[i * 128 + col];
#pragma unroll
    for (int k = 0; k < 64; ++k)
        cb = fmaf(res_b[(i - 1) * 64 + k], k1[k], cb);
    cb2[i * 128 + col] = cb;
}

// ---------------- repack2: build CV / RS / PH lane-major packs ----------------
__global__ void repack2(const float* __restrict__ conv_k, const float* __restrict__ res_w,
                        const float* __restrict__ skip_w, const float* __restrict__ out0_w,
                        const float* __restrict__ out1_w, float* __restrict__ ws) {
    const int bb = blockIdx.x, tid = threadIdx.x;
    float4* CV = (float4*)(ws + CV_OFF);
    float4* RS = (float4*)(ws + RS_OFF);
    float4* PH = (float4*)(ws + PH_OFF);
    const float* M = ws + MB_OFF;
    if (bb < NL) {
        const int i = bb, w = tid >> 6, l = tid & 63;
        const int c  = w * 8 + (l & 7);
        const int k0 = (l >> 3) * 8;
        float4* dst = CV + (size_t)i * (12 * 512) + tid;
#pragma unroll
        for (int half = 0; half < 2; ++half) {
            const int cc = c + half * 64;
#pragma unroll
            for (int jj = 0; jj < 2; ++jj) {
                const int kk = k0 + jj * 4;
                float4 a, b, m;
                a.x = conv_k[((size_t)(i * 2 + 0) * 64 + kk + 0) * 128 + cc];
                a.y = conv_k[((size_t)(i * 2 + 0) * 64 + kk + 1) * 128 + cc];
                a.z = conv_k[((size_t)(i * 2 + 0) * 64 + kk + 2) * 128 + cc];
                a.w = conv_k[((size_t)(i * 2 + 0) * 64 + kk + 3) * 128 + cc];
                b.x = conv_k[((size_t)(i * 2 + 1) * 64 + kk + 0) * 128 + cc];
                b.y = conv_k[((size_t)(i * 2 + 1) * 64 + kk + 1) * 128 + cc];
                b.z = conv_k[((size_t)(i * 2 + 1) * 64 + kk + 2) * 128 + cc];
                b.w = conv_k[((size_t)(i * 2 + 1) * 64 + kk + 3) * 128 + cc];
                m.x = M[((size_t)i * 64 + kk + 0) * 128 + cc];
                m.y = M[((size_t)i * 64 + kk + 1) * 128 + cc];
                m.z = M[((size_t)i * 64 + kk + 2) * 128 + cc];
                m.w = M[((size_t)i * 64 + kk + 3) * 128 + cc];
                dst[(half * 6 + 0 + jj) * 512] = a;
                dst[(half * 6 + 2 + jj) * 512] = b;
                dst[(half * 6 + 4 + jj) * 512] = m;
            }
        }
        float4* rdst = RS + (size_t)i * (10 * 512) + tid;
#pragma unroll
        for (int jj = 0; jj < 2; ++jj) {            // res col c, K-chunk k0
            float4 v; const int kk = k0 + jj * 4;
            v.x = res_w[((size_t)i * 64 + kk + 0) * 64 + c];
            v.y = res_w[((size_t)i * 64 + kk + 1) * 64 + c];
            v.z = res_w[((size_t)i * 64 + kk + 2) * 64 + c];
            v.w = res_w[((size_t)i * 64 + kk + 3) * 64 + c];
            rdst[jj * 512] = v;
        }
        const int s0 = w * 32 + (l & 15) * 2;
        const int ks = (l >> 4) * 16;
#pragma unroll
        for (int jj = 0; jj < 4; ++jj) {            // skip col s0
            float4 v; const int kk = ks + jj * 4;
            v.x = skip_w[((size_t)i * 64 + kk + 0) * 256 + s0];
            v.y = skip_w[((size_t)i * 64 + kk + 1) * 256 + s0];
            v.z = skip_w[((size_t)i * 64 + kk + 2) * 256 + s0];
            v.w = skip_w[((size_t)i * 64 + kk + 3) * 256 + s0];
            rdst[(2 + jj) * 512] = v;
        }
#pragma unroll
        for (int jj = 0; jj < 4; ++jj) {            // skip col s0+1
            float4 v; const int kk = ks + jj * 4; const int s1 = s0 + 1;
            v.x = skip_w[((size_t)i * 64 + kk + 0) * 256 + s1];
            v.y = skip_w[((size_t)i * 64 + kk + 1) * 256 + s1];
            v.z = skip_w[((size_t)i * 64 + kk + 2) * 256 + s1];
            v.w = skip_w[((size_t)i * 64 + kk + 3) * 256 + s1];
            rdst[(6 + jj) * 512] = v;
        }
    } else {
        if (tid >= 64) return;
        const int hb = bb - NL;                     // 0..15: [which][wave]
        const int which = hb >> 3, w = hb & 7, l = tid;
        const float* W = which ? out1_w : out0_w;
        float4* dst = PH + (size_t)hb * (32 * 64) + l;
        const int c  = w * 32 + (l & 31);
        const int kb = (l >> 5) * 128;
        for (int j = 0; j < 32; ++j) {
            float4 v; const int k0 = kb + j * 4;
            v.x = W[(size_t)(k0 + 0) * 256 + c];
            v.y = W[(size_t)(k0 + 1) * 256 + c];
            v.z = W[(size_t)(k0 + 2) * 256 + c];
            v.w = W[(size_t)(k0 + 3) * 256 + c];
            dst[j * 64] = v;
        }
    }
}

// ---------------- main generator: one phase per layer; 2-waves/EU register budget ----------------
__global__ __launch_bounds__(TPB)
__attribute__((amdgpu_waves_per_eu(2, 2)))   // 512 thr = 8 waves = 2/EU -> allow 256 VGPR, stop the 128-cap spill
void wavenet_gen(const int* __restrict__ seed,
                 const float* __restrict__ embed,
                 const float* __restrict__ res_b,
                 const float* __restrict__ skip_b,
                 const float* __restrict__ out0_b,
                 const float* __restrict__ out1_b,
                 const int* __restrict__ Tptr,
                 float* __restrict__ out,
                 float* __restrict__ ring,
                 const float4* __restrict__ cvp,
                 const float4* __restrict__ rsp,
                 const float4* __restrict__ php,
                 const float* __restrict__ cb2p)
{
    const int b   = blockIdx.x;
    const int tid = threadIdx.x;
    const int w   = tid >> 6;
    const int l   = tid & 63;
    const int T   = *Tptr;

    __shared__ __align__(16) float xl[2][64];        // xlast ping-pong
    __shared__ __align__(16) float yb[2][64];        // layer-input ping-pong (y_j in yb[j&1])
    __shared__ __align__(16) float gb[2][64];        // gate ping-pong (g_j in gb[j&1])
    __shared__ __align__(16) float skl[256];
    __shared__ __align__(16) float h0l[256];
    __shared__ __align__(16) float ebt[256 * 64];
    __shared__ __align__(16) float cb2S[NL * 128];
    __shared__ __align__(16) float rbS[NL * 64];
    __shared__ __align__(16) float o0bS[256], o1bS[256], sbtS[256];
    __shared__ float wmaxv[8];
    __shared__ int   wmaxi[8];

    float* q = ring + (size_t)b * (QROWS * 64);

    // ---- init ----
    {
        vf4* q4 = (vf4*)q;
        const vf4 z = (vf4){0.f, 0.f, 0.f, 0.f};
        for (int idx = tid; idx < QROWS * 64 / 4; idx += TPB)
            __builtin_nontemporal_store(z, &q4[idx]);
        const float4* s4; float4* d4;
        s4 = (const float4*)embed;  d4 = (float4*)ebt;
        for (int idx = tid; idx < 256 * 64 / 4; idx += TPB) d4[idx] = s4[idx];
        s4 = (const float4*)cb2p;   d4 = (float4*)cb2S;
        for (int idx = tid; idx < NL * 128 / 4; idx += TPB) d4[idx] = s4[idx];
        s4 = (const float4*)res_b;  d4 = (float4*)rbS;
        for (int idx = tid; idx < NL * 64 / 4; idx += TPB) d4[idx] = s4[idx];
        s4 = (const float4*)out0_b; d4 = (float4*)o0bS;
        for (int idx = tid; idx < 64; idx += TPB) d4[idx] = s4[idx];
        s4 = (const float4*)out1_b; d4 = (float4*)o1bS;
        for (int idx = tid; idx < 64; idx += TPB) d4[idx] = s4[idx];
        if (tid < 256) {
            float acc = 0.f;
            for (int i = 0; i < NL; ++i) acc += skip_b[i * 256 + tid];
            sbtS[tid] = acc;
        }
    }
    __syncthreads();
    if (tid < 64) {
        const int smp = seed[b];
        yb[0][tid] = ebt[smp * 64 + tid];   // y_0(t=0)
        yb[1][tid] = 0.f;
        xl[0][tid] = 0.f;                   // xlast_0(t=0)
        xl[1][tid] = 0.f;
        gb[0][tid] = 0.f;                   // avoid NaN*0 in layer-0 M-term
        gb[1][tid] = 0.f;
    }
    __syncthreads();

    WBc  CVa, CVb;
    WBrs RS;
    pf_cv(CVa, cvp, 0, tid);

    float* out_pred = out + (size_t)b * T;
    float* out_log  = out + (size_t)NB * T + (size_t)b * T * 256;

    const int c   = w * 8 + (l & 7);
    const int k0  = (l >> 3) * 8;          // conv/res K-chunk
    const int ks  = (l >> 4) * 16;         // skip K-chunk
    const int s0  = w * 32 + (l & 15) * 2;
    const int c2  = w * 32 + (l & 31);
    const int kb2 = (l >> 5) * 128;

    float skv0 = 0.f, skv1 = 0.f;

    for (int t = 0; t < T; ++t) {

        auto phase = [&](WBc& cur, WBc& nxt, const int i) {
            const int j = (i + 1 < NL) ? (i + 1) : 0;
            // ---- issue: ring read (xlast_j) FIRST, then RS_{i-1}, then CV_j ----
            float xln = 0.f;
            if (w == 7) {
                const int dj = 1 << (j & 7);
                const int s  = (i == NL - 1) ? (t + 1) : t;
                const int row = 255 * (j >> 3) + (dj - 1) + (s & (dj - 1));
                xln = __builtin_nontemporal_load(&q[(size_t)row * 64 + l]);
            }
            if (i) pf_rs(RS, rsp, i - 1, tid);
            pf_cv(nxt, cvp, j, tid);
            if (w == 6 && i) {              // push row(i-1, t) = y_{i-1}(t)
                const int dp = 1 << ((i - 1) & 7);
                const int row = 255 * ((i - 1) >> 3) + (dp - 1) + (t & (dp - 1));
                __builtin_nontemporal_store(yb[(i - 1) & 1][l], &q[(size_t)row * 64 + l]);
            }
            const int ybi = i ? ((i - 1) & 1) : 0;   // buffer holding y_{i-1} (or y_0 for i=0)
            const int gbi = (i - 1) & 1;             // buffer holding g_{i-1} (garbage*0 for i=0)
            // ---- 3-term conv ----
            const float4 xl0 = *(const float4*)&xl[i & 1][k0];
            const float4 xl1 = *(const float4*)&xl[i & 1][k0 + 4];
            const float4 yp0 = *(const float4*)&yb[ybi][k0];
            const float4 yp1 = *(const float4*)&yb[ybi][k0 + 4];
            const float4 gp0 = *(const float4*)&gb[gbi][k0];
            const float4 gp1 = *(const float4*)&gb[gbi][k0 + 4];
            float4 aA = make_float4(0.f, 0.f, 0.f, 0.f);
            float4 aB = make_float4(0.f, 0.f, 0.f, 0.f);
            fma4(aA, xl0, cur.v[0]); fma4(aA, xl1, cur.v[1]);
            fma4(aA, yp0, cur.v[2]); fma4(aA, yp1, cur.v[3]);
            fma4(aA, gp0, cur.v[4]); fma4(aA, gp1, cur.v[5]);
            fma4(aB, xl0, cur.v[6]); fma4(aB, xl1, cur.v[7]);
            fma4(aB, yp0, cur.v[8]); fma4(aB, yp1, cur.v[9]);
            fma4(aB, gp0, cur.v[10]); fma4(aB, gp1, cur.v[11]);
            float hA = hadd4(aA), hB = hadd4(aB);
            hA += __shfl_xor(hA, 8);  hB += __shfl_xor(hB, 8);
            hA += __shfl_xor(hA, 16); hB += __shfl_xor(hB, 16);
            hA += __shfl_xor(hA, 32); hB += __shfl_xor(hB, 32);
            hA += cb2S[i * 128 + c];
            hB += cb2S[i * 128 + 64 + c];
            const float g = tanhf(hA) * (1.f / (1.f + expf(-hB)));
            // ---- deferred res + skip of layer i-1 ----
            float ynew = 0.f;
            if (i) {
                float4 ra = make_float4(0.f, 0.f, 0.f, 0.f);
                fma4(ra, gp0, RS.v[0]); fma4(ra, gp1, RS.v[1]);
                float racc = hadd4(ra);
                racc += __shfl_xor(racc, 8);
                racc += __shfl_xor(racc, 16);
                racc += __shfl_xor(racc, 32);
                ynew = yb[ybi][c] + racc + rbS[(i - 1) * 64 + c];
                const float4 gs0 = *(const float4*)&gb[gbi][ks];
                const float4 gs1 = *(const float4*)&gb[gbi][ks + 4];
                const float4 gs2 = *(const float4*)&gb[gbi][ks + 8];
                const float4 gs3 = *(const float4*)&gb[gbi][ks + 12];
                float4 sa0 = make_float4(0.f, 0.f, 0.f, 0.f);
                float4 sa1 = make_float4(0.f, 0.f, 0.f, 0.f);
                fma4(sa0, gs0, RS.v[2]); fma4(sa0, gs1, RS.v[3]);
                fma4(sa0, gs2, RS.v[4]); fma4(sa0, gs3, RS.v[5]);
                fma4(sa1, gs0, RS.v[6]); fma4(sa1, gs1, RS.v[7]);
                fma4(sa1, gs2, RS.v[8]); fma4(sa1, gs3, RS.v[9]);
                float ss0 = hadd4(sa0), ss1 = hadd4(sa1);
                ss0 += __shfl_xor(ss0, 16); ss1 += __shfl_xor(ss1, 16);
                ss0 += __shfl_xor(ss0, 32); ss1 += __shfl_xor(ss1, 32);
                skv0 += ss0;
                skv1 += ss1;
            }
            // ---- publish ----
            if (l < 8) gb[i & 1][w * 8 + l] = g;
            if (i && l < 8) yb[i & 1][w * 8 + l] = ynew;
            if (w == 7) xl[j & 1][l] = xln;
            bar();
        };

#pragma unroll 1
        for (int ii = 0; ii < NL; ii += 2) {
            phase(CVa, CVb, ii);
            phase(CVb, CVa, ii + 1);
        }

        // ---------------- head phase A: skip_23, finalize sk, push row(23) ----------------
        {
            pf_rs(RS, rsp, NL - 1, tid);
            const float4 gs0 = *(const float4*)&gb[1][ks];
            const float4 gs1 = *(const float4*)&gb[1][ks + 4];
            const float4 gs2 = *(const float4*)&gb[1][ks + 8];
            const float4 gs3 = *(const float4*)&gb[1][ks + 12];
            float4 sa0 = make_float4(0.f, 0.f, 0.f, 0.f);
            float4 sa1 = make_float4(0.f, 0.f, 0.f, 0.f);
            fma4(sa0, gs0, RS.v[2]); fma4(sa0, gs1, RS.v[3]);
            fma4(sa0, gs2, RS.v[4]); fma4(sa0, gs3, RS.v[5]);
            fma4(sa1, gs0, RS.v[6]); fma4(sa1, gs1, RS.v[7]);
            fma4(sa1, gs2, RS.v[8]); fma4(sa1, gs3, RS.v[9]);
            float ss0 = hadd4(sa0), ss1 = hadd4(sa1);
            ss0 += __shfl_xor(ss0, 16); ss1 += __shfl_xor(ss1, 16);
            ss0 += __shfl_xor(ss0, 32); ss1 += __shfl_xor(ss1, 32);
            skv0 += ss0;
            skv1 += ss1;
            if (l < 16) {
                skl[s0] = skv0 + sbtS[s0];
                skl[s0 + 1] = skv1 + sbtS[s0 + 1];
            }
            skv0 = 0.f; skv1 = 0.f;
            if (w == 6) {                   // push row(23, t) = y_23(t)
                const int row = 510 + 127 + (t & 127);
                __builtin_nontemporal_store(yb[1][l], &q[(size_t)row * 64 + l]);
            }
            bar();
        }
        // ---------------- head B: GEMV1 ----------------
        {
            const float4* hp = php + ((size_t)w * 32) * 64 + l;
            float4 ha = make_float4(0.f, 0.f, 0.f, 0.f);
#pragma unroll 8
            for (int cc = 0; cc < 32; ++cc) {
                float4 wv = hp[cc * 64];
                float4 sv = *(const float4*)&skl[kb2 + cc * 4];
                fma4(ha, sv, wv);
            }
            float hs = hadd4(ha);
            hs += __shfl_xor(hs, 32);
            const float h0 = fmaxf(hs + o0bS[c2], 0.f);
            if (l < 32) h0l[c2] = h0;
        }
        bar();
        // ---------------- head C: GEMV2 + wave argmax ----------------
        {
            const float4* hp = php + ((size_t)(8 + w) * 32) * 64 + l;
            float4 la = make_float4(0.f, 0.f, 0.f, 0.f);
#pragma unroll 8
            for (int cc = 0; cc < 32; ++cc) {
                float4 wv = hp[cc * 64];
                float4 hv = *(const float4*)&h0l[kb2 + cc * 4];
                fma4(la, hv, wv);
            }
            float ls = hadd4(la);
            ls += __shfl_xor(ls, 32);
            const float logit = ls + o1bS[c2];
            if (l < 32)
                __builtin_nontemporal_store(logit, &out_log[(size_t)t * 256 + c2]);
            float bv = logit; int bi = c2;
#pragma unroll
            for (int off = 1; off <= 16; off <<= 1) {
                const float ov = __shfl_xor(bv, off);
                const int   oi = __shfl_xor(bi, off);
                if (ov > bv || (ov == bv && oi < bi)) { bv = ov; bi = oi; }
            }
            if (l == 0) { wmaxv[w] = bv; wmaxi[w] = bi; }
        }
        bar();
        // ---------------- head D: final argmax, y_0(t+1), mu-law ----------------
        {
            float fv = wmaxv[0]; int fi = wmaxi[0];
#pragma unroll
            for (int ww = 1; ww < 8; ++ww) {
                const float vv = wmaxv[ww]; const int vi = wmaxi[ww];
                if (vv > fv || (vv == fv && vi < fi)) { fv = vv; fi = vi; }
            }
            if (tid < 64) yb[0][tid] = ebt[fi * 64 + tid];   // y_0 of next step
            if (tid == 0) {
                const float mw = (float)fi * (2.0f / 255.0f) - 1.0f;
                const float a  = fabsf(mw);
                const float p  = (exp2f(8.0f * a) - 1.0f) * (1.0f / 255.0f);
                __builtin_nontemporal_store((mw < 0.f) ? -p : p, &out_pred[t]);
            }
        }
        bar();
    }
}

extern "C" void kernel_launch(void* const* d_in, const int* in_sizes, int n_in,
                              void* d_out, int out_size, void* d_ws, size_t ws_size,
                              hipStream_t stream) {
    const int*   seed   = (const int*)  d_in[0];
    const float* embed  = (const float*)d_in[1];
    const float* conv_k = (const float*)d_in[2];
    const float* conv_b = (const float*)d_in[3];
    const float* res_w  = (const float*)d_in[4];
    const float* res_b  = (const float*)d_in[5];
    const float* skip_w = (const float*)d_in[6];
    const float* skip_b = (const float*)d_in[7];
    const float* out0_w = (const float*)d_in[8];
    const float* out0_b = (const float*)d_in[9];
    const float* out1_w = (const float*)d_in[10];
    const float* out1_b = (const float*)d_in[11];
    const int*   Tptr   = (const int*)  d_in[12];

    float* ws = (float*)d_ws;
    float* ring = ws;
    const float4* cvp  = (const float4*)(ws + CV_OFF);
    const float4* rsp  = (const float4*)(ws + RS_OFF);
    const float4* php  = (const float4*)(ws + PH_OFF);
    const float*  cb2p = ws + CB2_OFF;

    repack1<<<dim3(NL), dim3(128), 0, stream>>>(conv_k, res_w, conv_b, res_b, ws);
    repack2<<<dim3(NL + 16), dim3(512), 0, stream>>>(conv_k, res_w, skip_w, out0_w, out1_w, ws);

    wavenet_gen<<<dim3(NB), dim3(TPB), 0, stream>>>(
        seed, embed, res_b, skip_b, out0_b, out1_b, Tptr,
        (float*)d_out, ring, cvp, rsp, php, cb2p);
}